// Round 1
// baseline (611.534 us; speedup 1.0000x reference)
//
#include <hip/hip_runtime.h>
#include <hip/hip_bf16.h>

#define DD 768
#define HH 3072
#define NE 8
#define TOPK 2

#define BM 128
#define BN 128
#define BK 64

typedef __attribute__((ext_vector_type(8))) short short8;
typedef __attribute__((ext_vector_type(4))) float f32x4;

static __device__ __forceinline__ unsigned short f2bf(float v) {
    __hip_bfloat16 b = __float2bfloat16(v);
    return *reinterpret_cast<unsigned short*>(&b);
}

// ---------------- weight conversion fp32 -> bf16 ----------------
__global__ __launch_bounds__(256) void convert_kernel(
    const float* __restrict__ w1, const float* __restrict__ w2,
    unsigned short* __restrict__ w1b, unsigned short* __restrict__ w2b, size_t n)
{
    size_t tid = (size_t)blockIdx.x * blockDim.x + threadIdx.x;
    size_t stride = (size_t)gridDim.x * blockDim.x;
    size_t quarter = n / 4;            // float4 count per tensor
    size_t tot = 2 * quarter;
    for (size_t j = tid; j < tot; j += stride) {
        const float* src; unsigned short* dst; size_t off;
        if (j < quarter) { src = w1; dst = w1b; off = j * 4; }
        else             { src = w2; dst = w2b; off = (j - quarter) * 4; }
        float4 v = *reinterpret_cast<const float4*>(&src[off]);
        ushort4 o;
        o.x = f2bf(v.x); o.y = f2bf(v.y); o.z = f2bf(v.z); o.w = f2bf(v.w);
        *reinterpret_cast<ushort4*>(&dst[off]) = o;
    }
}

// ---------------- init control block + token_map ----------------
__global__ __launch_bounds__(256) void init_kernel(int* token_map, int* ctrl, int maxP)
{
    int i = blockIdx.x * blockDim.x + threadIdx.x;
    if (i < maxP) token_map[i] = -1;
    if (i < 32) ctrl[i] = 0;   // [0..8) counts, [8..16) cursors, [16..25) offsets
}

// ---------------- gate: logits, top-2, softmax ----------------
__global__ __launch_bounds__(256) void gate_kernel(
    const float* __restrict__ x, const float* __restrict__ gw, const float* __restrict__ gb,
    int* __restrict__ topk_idx, float* __restrict__ topk_w, int* __restrict__ ctrl, int T)
{
    int t = blockIdx.x * 4 + (threadIdx.x >> 6);
    int lane = threadIdx.x & 63;
    if (t >= T) return;
    float acc[NE];
#pragma unroll
    for (int e = 0; e < NE; ++e) acc[e] = 0.f;
    const float* xr = x + (size_t)t * DD;
    for (int d = lane; d < DD; d += 64) {
        float xv = xr[d];
#pragma unroll
        for (int e = 0; e < NE; ++e) acc[e] += xv * gw[e * DD + d];
    }
#pragma unroll
    for (int e = 0; e < NE; ++e) {
        float v = acc[e];
        for (int off = 32; off; off >>= 1) v += __shfl_xor(v, off, 64);
        acc[e] = v;
    }
    if (lane == 0) {
        float lg[NE];
#pragma unroll
        for (int e = 0; e < NE; ++e) lg[e] = acc[e] + gb[e];
        int i0 = 0;
#pragma unroll
        for (int e = 1; e < NE; ++e) if (lg[e] > lg[i0]) i0 = e;
        int i1 = -1;
#pragma unroll
        for (int e = 0; e < NE; ++e) {
            if (e == i0) continue;
            if (i1 < 0 || lg[e] > lg[i1]) i1 = e;
        }
        float m = lg[i0];
        float e0 = __expf(lg[i0] - m), e1 = __expf(lg[i1] - m);
        float s = e0 + e1;
        topk_idx[2 * t]     = i0;
        topk_idx[2 * t + 1] = i1;
        topk_w[2 * t]       = e0 / s;
        topk_w[2 * t + 1]   = e1 / s;
        atomicAdd(&ctrl[i0], 1);
        atomicAdd(&ctrl[i1], 1);
    }
}

// ---------------- offsets (padded to 128 per expert) ----------------
__global__ void offsets_kernel(int* ctrl)
{
    if (threadIdx.x == 0 && blockIdx.x == 0) {
        int acc = 0;
        for (int e = 0; e < NE; ++e) {
            ctrl[16 + e] = acc;
            acc += (ctrl[e] + 127) & ~127;
        }
        ctrl[16 + NE] = acc;
    }
}

// ---------------- scatter assignments to expert segments ----------------
__global__ __launch_bounds__(256) void scatter_kernel(
    const int* __restrict__ topk_idx, const float* __restrict__ topk_w,
    int* ctrl, int* token_map, int* pos_of, float* wpos, int nA)
{
    int a = blockIdx.x * blockDim.x + threadIdx.x;
    if (a >= nA) return;
    int e = topk_idx[a];
    int p = ctrl[16 + e] + atomicAdd(&ctrl[8 + e], 1);
    token_map[p] = a;
    pos_of[a] = p;
    wpos[p] = topk_w[a];
}

// ---------------- gather x rows -> bf16 Xe ----------------
__global__ __launch_bounds__(256) void gather_kernel(
    const float* __restrict__ x, const int* __restrict__ token_map,
    unsigned short* __restrict__ Xe, int maxP)
{
    int i = blockIdx.x * blockDim.x + threadIdx.x;
    int total = maxP * (DD / 4);
    if (i >= total) return;
    int r = i / (DD / 4);
    int c = (i % (DD / 4)) * 4;
    int a = token_map[r];
    ushort4 o;
    if (a < 0) {
        o.x = o.y = o.z = o.w = 0;
    } else {
        float4 v = *reinterpret_cast<const float4*>(&x[(size_t)(a >> 1) * DD + c]);
        o.x = f2bf(v.x); o.y = f2bf(v.y); o.z = f2bf(v.z); o.w = f2bf(v.w);
    }
    *reinterpret_cast<ushort4*>(&Xe[(size_t)r * DD + c]) = o;
}

// ---------------- staging: 128 rows x 64 cols bf16 tile -> LDS ----------------
// Linear LDS dest (global_load_lds requirement) + inverse-XOR-swizzled per-lane
// global source. Logical chunk (row, kc) lives at LDS chunk row*8 + (kc ^ (row&7)),
// spreading a column-slice read across all 32 banks. Reader applies the same XOR.
static __device__ __forceinline__ void stage64(
    const unsigned short* __restrict__ gbase, int ld, unsigned short* lds)
{
    int tid = threadIdx.x;
#pragma unroll
    for (int r = 0; r < 4; ++r) {
        int j = (r << 8) + tid;           // dest 16B-chunk index, 0..1023
        int row = j >> 3;
        int kc = (j & 7) ^ (row & 7);     // inverse swizzle on SOURCE
        __builtin_amdgcn_global_load_lds(
            (const __attribute__((address_space(1))) void*)(gbase + (size_t)row * ld + (kc << 3)),
            (__attribute__((address_space(3))) void*)(lds + ((size_t)j << 3)),
            16, 0, 0);
    }
}

// ---------------- 2-phase double-buffered GEMM core ----------------
// Per K-tile: issue next-tile STAGE first, then ds_read current, 32 MFMA,
// single __syncthreads() (drains vmcnt for the staged tile). Load latency
// hides under ds_read+MFMA instead of sitting exposed before compute.
static __device__ __forceinline__ void gemm_core(
    const unsigned short* __restrict__ Abase,
    const unsigned short* __restrict__ Bbase,
    int ld, int nt,
    unsigned short* As0, unsigned short* Bs0,   // each [2][BM*BK]
    f32x4 acc[4][4], int wr, int wc, int fr, int fq)
{
    const int BUF = BM * BK;   // 8192 shorts
    int sw = fr & 7;

    stage64(Abase, ld, As0);
    stage64(Bbase, ld, Bs0);
    __syncthreads();

    int cur = 0;
    for (int t = 0; t < nt; ++t) {
        if (t + 1 < nt) {
            const unsigned short* An = Abase + (size_t)(t + 1) * BK;
            const unsigned short* Bn = Bbase + (size_t)(t + 1) * BK;
            stage64(An, ld, As0 + (cur ^ 1) * BUF);
            stage64(Bn, ld, Bs0 + (cur ^ 1) * BUF);
        }
        const unsigned short* A = As0 + cur * BUF;
        const unsigned short* B = Bs0 + cur * BUF;
        short8 a[2][4], b[2][4];
#pragma unroll
        for (int ks = 0; ks < 2; ++ks) {
            int kc = ks * 4 + fq;
#pragma unroll
            for (int m = 0; m < 4; ++m) {
                int row = wr + m * 16 + fr;
                a[ks][m] = *reinterpret_cast<const short8*>(&A[((row << 3) + (kc ^ sw)) << 3]);
            }
#pragma unroll
            for (int n = 0; n < 4; ++n) {
                int row = wc + n * 16 + fr;
                b[ks][n] = *reinterpret_cast<const short8*>(&B[((row << 3) + (kc ^ sw)) << 3]);
            }
        }
        __builtin_amdgcn_s_setprio(1);
#pragma unroll
        for (int ks = 0; ks < 2; ++ks)
#pragma unroll
            for (int m = 0; m < 4; ++m)
#pragma unroll
                for (int n = 0; n < 4; ++n)
                    acc[m][n] = __builtin_amdgcn_mfma_f32_16x16x32_bf16(
                        a[ks][m], b[ks][n], acc[m][n], 0, 0, 0);
        __builtin_amdgcn_s_setprio(0);
        __syncthreads();
        cur ^= 1;
    }
}

// ---------------- GEMM1: H1 = gelu(Xe @ w1^T + b1), bf16 out ----------------
__global__ __launch_bounds__(256, 2) void gemm1_kernel(
    const unsigned short* __restrict__ Xe, const unsigned short* __restrict__ W1b,
    const float* __restrict__ b1, unsigned short* __restrict__ H1,
    const int* __restrict__ offs)
{
    int e = blockIdx.z;
    int segbase = offs[e];
    int segcnt = offs[e + 1] - segbase;
    if ((int)blockIdx.x * BM >= segcnt) return;
    int rowbase = segbase + blockIdx.x * BM;
    int colbase = blockIdx.y * BN;
    const unsigned short* Abase = Xe + (size_t)rowbase * DD;
    const unsigned short* Bbase = W1b + (size_t)e * HH * DD + (size_t)colbase * DD;

    __shared__ unsigned short As[2][BM * BK];
    __shared__ unsigned short Bs[2][BN * BK];

    int tid = threadIdx.x, lane = tid & 63, w = tid >> 6;
    int wr = (w >> 1) * 64, wc = (w & 1) * 64;
    int fr = lane & 15, fq = lane >> 4;

    f32x4 acc[4][4];
#pragma unroll
    for (int m = 0; m < 4; ++m)
#pragma unroll
        for (int n = 0; n < 4; ++n) acc[m][n] = (f32x4){0.f, 0.f, 0.f, 0.f};

    gemm_core(Abase, Bbase, DD, DD / BK, &As[0][0], &Bs[0][0], acc, wr, wc, fr, fq);

#pragma unroll
    for (int m = 0; m < 4; ++m) {
        int row0 = rowbase + wr + m * 16 + fq * 4;
#pragma unroll
        for (int n = 0; n < 4; ++n) {
            int col = colbase + wc + n * 16 + fr;
            float bb = b1[e * HH + col];
#pragma unroll
            for (int r = 0; r < 4; ++r) {
                float v = acc[m][n][r] + bb;
                v = 0.5f * v * (1.f + erff(v * 0.70710678118f));
                H1[(size_t)(row0 + r) * HH + col] = f2bf(v);
            }
        }
    }
}

// ---------------- GEMM2: Yb = wpos * (H1 @ w2^T + b2), f32 out ----------------
__global__ __launch_bounds__(256, 2) void gemm2_kernel(
    const unsigned short* __restrict__ H1, const unsigned short* __restrict__ W2b,
    const float* __restrict__ b2, const float* __restrict__ wpos,
    float* __restrict__ Yb, const int* __restrict__ offs)
{
    int e = blockIdx.z;
    int segbase = offs[e];
    int segcnt = offs[e + 1] - segbase;
    if ((int)blockIdx.x * BM >= segcnt) return;
    int rowbase = segbase + blockIdx.x * BM;
    int colbase = blockIdx.y * BN;
    const unsigned short* Abase = H1 + (size_t)rowbase * HH;
    const unsigned short* Bbase = W2b + (size_t)e * DD * HH + (size_t)colbase * HH;

    __shared__ unsigned short As[2][BM * BK];
    __shared__ unsigned short Bs[2][BN * BK];

    int tid = threadIdx.x, lane = tid & 63, w = tid >> 6;
    int wr = (w >> 1) * 64, wc = (w & 1) * 64;
    int fr = lane & 15, fq = lane >> 4;

    f32x4 acc[4][4];
#pragma unroll
    for (int m = 0; m < 4; ++m)
#pragma unroll
        for (int n = 0; n < 4; ++n) acc[m][n] = (f32x4){0.f, 0.f, 0.f, 0.f};

    gemm_core(Abase, Bbase, HH, HH / BK, &As[0][0], &Bs[0][0], acc, wr, wc, fr, fq);

#pragma unroll
    for (int m = 0; m < 4; ++m) {
        int row0 = rowbase + wr + m * 16 + fq * 4;
#pragma unroll
        for (int n = 0; n < 4; ++n) {
            int col = colbase + wc + n * 16 + fr;
            float bb = b2[e * DD + col];
#pragma unroll
            for (int r = 0; r < 4; ++r) {
                float v = acc[m][n][r] + bb;
                Yb[(size_t)(row0 + r) * DD + col] = wpos[row0 + r] * v;
            }
        }
    }
}

// ---------------- combine: out[t] = Yb[pos0] + Yb[pos1]; bias passthrough ----------------
__global__ __launch_bounds__(256) void combine_kernel(
    const float* __restrict__ Yb, const int* __restrict__ pos_of,
    const float* __restrict__ bias, float* __restrict__ out, int T)
{
    int i = blockIdx.x * blockDim.x + threadIdx.x;
    int total = T * (DD / 4);
    if (i < total) {
        int t = i / (DD / 4);
        int c = (i % (DD / 4)) * 4;
        int p0 = pos_of[2 * t], p1 = pos_of[2 * t + 1];
        float4 v0 = *reinterpret_cast<const float4*>(&Yb[(size_t)p0 * DD + c]);
        float4 v1 = *reinterpret_cast<const float4*>(&Yb[(size_t)p1 * DD + c]);
        float4 o;
        o.x = v0.x + v1.x; o.y = v0.y + v1.y; o.z = v0.z + v1.z; o.w = v0.w + v1.w;
        *reinterpret_cast<float4*>(&out[(size_t)t * DD + c]) = o;
    } else if (i < total + DD / 4) {
        int c = (i - total) * 4;
        *reinterpret_cast<float4*>(&out[(size_t)T * DD + c]) =
            *reinterpret_cast<const float4*>(&bias[c]);
    }
}

extern "C" void kernel_launch(void* const* d_in, const int* in_sizes, int n_in,
                              void* d_out, int out_size, void* d_ws, size_t ws_size,
                              hipStream_t stream)
{
    const float* x    = (const float*)d_in[0];
    const float* gw   = (const float*)d_in[1];
    const float* gb   = (const float*)d_in[2];
    const float* w1   = (const float*)d_in[3];
    const float* b1   = (const float*)d_in[4];
    const float* w2   = (const float*)d_in[5];
    const float* b2   = (const float*)d_in[6];
    const float* bias = (const float*)d_in[7];
    float* out = (float*)d_out;

    int T = in_sizes[0] / DD;
    int nA = T * TOPK;
    int maxP = nA + NE * 128;

    char* ws = (char*)d_ws;
    size_t off = 0;
    auto alloc = [&](size_t bytes) -> char* {
        char* p = ws + off;
        off += (bytes + 255) & ~(size_t)255;
        return p;
    };
    unsigned short* w1b = (unsigned short*)alloc((size_t)NE * HH * DD * 2);
    unsigned short* w2b = (unsigned short*)alloc((size_t)NE * DD * HH * 2);
    unsigned short* Xe  = (unsigned short*)alloc((size_t)maxP * DD * 2);
    unsigned short* H1  = (unsigned short*)alloc((size_t)maxP * HH * 2);
    float*  Yb          = (float*)alloc((size_t)maxP * DD * 4);
    int*    topk_idx    = (int*)alloc((size_t)nA * 4);
    float*  topk_w      = (float*)alloc((size_t)nA * 4);
    int*    pos_of      = (int*)alloc((size_t)nA * 4);
    float*  wpos        = (float*)alloc((size_t)maxP * 4);
    int*    token_map   = (int*)alloc((size_t)maxP * 4);
    int*    ctrl        = (int*)alloc(32 * 4);

    size_t nW = (size_t)NE * HH * DD;

    hipLaunchKernelGGL(convert_kernel, dim3(4096), dim3(256), 0, stream,
                       w1, w2, w1b, w2b, nW);
    hipLaunchKernelGGL(init_kernel, dim3((maxP + 255) / 256), dim3(256), 0, stream,
                       token_map, ctrl, maxP);
    hipLaunchKernelGGL(gate_kernel, dim3((T + 3) / 4), dim3(256), 0, stream,
                       x, gw, gb, topk_idx, topk_w, ctrl, T);
    hipLaunchKernelGGL(offsets_kernel, dim3(1), dim3(64), 0, stream, ctrl);
    hipLaunchKernelGGL(scatter_kernel, dim3((nA + 255) / 256), dim3(256), 0, stream,
                       topk_idx, topk_w, ctrl, token_map, pos_of, wpos, nA);
    hipLaunchKernelGGL(gather_kernel, dim3((maxP * (DD / 4) + 255) / 256), dim3(256), 0, stream,
                       x, token_map, Xe, maxP);
    hipLaunchKernelGGL(gemm1_kernel, dim3(32, HH / BN, NE), dim3(256), 0, stream,
                       Xe, w1b, b1, H1, ctrl + 16);
    hipLaunchKernelGGL(gemm2_kernel, dim3(32, DD / BN, NE), dim3(256), 0, stream,
                       H1, w2b, b2, wpos, Yb, ctrl + 16);
    hipLaunchKernelGGL(combine_kernel, dim3((T * (DD / 4) + DD / 4 + 255) / 256, 1, 1), dim3(256), 0, stream,
                       Yb, pos_of, bias, out, T);
}

// Round 2
// 564.995 us; speedup vs baseline: 1.0824x; 1.0824x over previous
//
#include <hip/hip_runtime.h>
#include <hip/hip_bf16.h>

#define DD 768
#define HH 3072
#define NE 8
#define TOPK 2

#define BM 128
#define BN 128
#define BK 64
#define GX 16   // row-blocks per expert (capacity 16*128 = 2048 rows/expert)

typedef __attribute__((ext_vector_type(8))) short short8;
typedef __attribute__((ext_vector_type(4))) float f32x4;

static __device__ __forceinline__ unsigned short f2bf(float v) {
    __hip_bfloat16 b = __float2bfloat16(v);
    return *reinterpret_cast<unsigned short*>(&b);
}

// ---------------- weight conversion fp32 -> bf16 ----------------
__global__ __launch_bounds__(256) void convert_kernel(
    const float* __restrict__ w1, const float* __restrict__ w2,
    unsigned short* __restrict__ w1b, unsigned short* __restrict__ w2b, size_t n)
{
    size_t tid = (size_t)blockIdx.x * blockDim.x + threadIdx.x;
    size_t stride = (size_t)gridDim.x * blockDim.x;
    size_t quarter = n / 4;            // float4 count per tensor
    size_t tot = 2 * quarter;
    for (size_t j = tid; j < tot; j += stride) {
        const float* src; unsigned short* dst; size_t off;
        if (j < quarter) { src = w1; dst = w1b; off = j * 4; }
        else             { src = w2; dst = w2b; off = (j - quarter) * 4; }
        float4 v = *reinterpret_cast<const float4*>(&src[off]);
        ushort4 o;
        o.x = f2bf(v.x); o.y = f2bf(v.y); o.z = f2bf(v.z); o.w = f2bf(v.w);
        *reinterpret_cast<ushort4*>(&dst[off]) = o;
    }
}

// ---------------- init control block + token_map ----------------
__global__ __launch_bounds__(256) void init_kernel(int* token_map, int* ctrl, int maxP)
{
    int i = blockIdx.x * blockDim.x + threadIdx.x;
    if (i < maxP) token_map[i] = -1;
    if (i < 32) ctrl[i] = 0;   // [0..8) counts, [8..16) cursors, [16..25) offsets
}

// ---------------- gate: logits, top-2, softmax ----------------
__global__ __launch_bounds__(256) void gate_kernel(
    const float* __restrict__ x, const float* __restrict__ gw, const float* __restrict__ gb,
    int* __restrict__ topk_idx, float* __restrict__ topk_w, int* __restrict__ ctrl, int T)
{
    int t = blockIdx.x * 4 + (threadIdx.x >> 6);
    int lane = threadIdx.x & 63;
    if (t >= T) return;
    float acc[NE];
#pragma unroll
    for (int e = 0; e < NE; ++e) acc[e] = 0.f;
    const float* xr = x + (size_t)t * DD;
    for (int d = lane; d < DD; d += 64) {
        float xv = xr[d];
#pragma unroll
        for (int e = 0; e < NE; ++e) acc[e] += xv * gw[e * DD + d];
    }
#pragma unroll
    for (int e = 0; e < NE; ++e) {
        float v = acc[e];
        for (int off = 32; off; off >>= 1) v += __shfl_xor(v, off, 64);
        acc[e] = v;
    }
    if (lane == 0) {
        float lg[NE];
#pragma unroll
        for (int e = 0; e < NE; ++e) lg[e] = acc[e] + gb[e];
        int i0 = 0;
#pragma unroll
        for (int e = 1; e < NE; ++e) if (lg[e] > lg[i0]) i0 = e;
        int i1 = -1;
#pragma unroll
        for (int e = 0; e < NE; ++e) {
            if (e == i0) continue;
            if (i1 < 0 || lg[e] > lg[i1]) i1 = e;
        }
        float m = lg[i0];
        float e0 = __expf(lg[i0] - m), e1 = __expf(lg[i1] - m);
        float s = e0 + e1;
        topk_idx[2 * t]     = i0;
        topk_idx[2 * t + 1] = i1;
        topk_w[2 * t]       = e0 / s;
        topk_w[2 * t + 1]   = e1 / s;
        atomicAdd(&ctrl[i0], 1);
        atomicAdd(&ctrl[i1], 1);
    }
}

// ---------------- offsets (padded to 128 per expert) ----------------
__global__ void offsets_kernel(int* ctrl)
{
    if (threadIdx.x == 0 && blockIdx.x == 0) {
        int acc = 0;
        for (int e = 0; e < NE; ++e) {
            ctrl[16 + e] = acc;
            acc += (ctrl[e] + 127) & ~127;
        }
        ctrl[16 + NE] = acc;
    }
}

// ---------------- scatter assignments to expert segments ----------------
__global__ __launch_bounds__(256) void scatter_kernel(
    const int* __restrict__ topk_idx, const float* __restrict__ topk_w,
    int* ctrl, int* token_map, int* pos_of, float* wpos, int nA)
{
    int a = blockIdx.x * blockDim.x + threadIdx.x;
    if (a >= nA) return;
    int e = topk_idx[a];
    int p = ctrl[16 + e] + atomicAdd(&ctrl[8 + e], 1);
    token_map[p] = a;
    pos_of[a] = p;
    wpos[p] = topk_w[a];
}

// ---------------- gather x rows -> bf16 Xe ----------------
__global__ __launch_bounds__(256) void gather_kernel(
    const float* __restrict__ x, const int* __restrict__ token_map,
    unsigned short* __restrict__ Xe, int maxP)
{
    int i = blockIdx.x * blockDim.x + threadIdx.x;
    int total = maxP * (DD / 4);
    if (i >= total) return;
    int r = i / (DD / 4);
    int c = (i % (DD / 4)) * 4;
    int a = token_map[r];
    ushort4 o;
    if (a < 0) {
        o.x = o.y = o.z = o.w = 0;
    } else {
        float4 v = *reinterpret_cast<const float4*>(&x[(size_t)(a >> 1) * DD + c]);
        o.x = f2bf(v.x); o.y = f2bf(v.y); o.z = f2bf(v.z); o.w = f2bf(v.w);
    }
    *reinterpret_cast<ushort4*>(&Xe[(size_t)r * DD + c]) = o;
}

// ---------------- staging: 128 rows x 64 cols bf16 tile -> LDS ----------------
// Linear LDS dest (global_load_lds requirement) + inverse-XOR-swizzled per-lane
// global source. Logical chunk (row, kc) lives at LDS chunk row*8 + (kc ^ (row&7)).
// Reader applies the same XOR. Verified conflict-free (round 1: SQ_LDS_BANK_CONFLICT=0).
static __device__ __forceinline__ void stage64(
    const unsigned short* __restrict__ gbase, int ld, unsigned short* lds)
{
    int tid = threadIdx.x;
#pragma unroll
    for (int r = 0; r < 4; ++r) {
        int j = (r << 8) + tid;           // dest 16B-chunk index, 0..1023
        int row = j >> 3;
        int kc = (j & 7) ^ (row & 7);     // inverse swizzle on SOURCE
        __builtin_amdgcn_global_load_lds(
            (const __attribute__((address_space(1))) void*)(gbase + (size_t)row * ld + (kc << 3)),
            (__attribute__((address_space(3))) void*)(lds + ((size_t)j << 3)),
            16, 0, 0);
    }
}

// ---------------- depth-2 pipelined GEMM core (3 rotating LDS buffers) ----------------
// Iter t: issue stage(t+2), s_waitcnt vmcnt(16) -> tile t landed (2 tile-pairs stay
// in flight, never drained in-loop), s_barrier, ds_read tile t, MFMA, lgkm fence,
// s_barrier. Loads get ~2 full iterations (~900 cy) to land -> covers HBM miss.
static __device__ __forceinline__ void gemm_core(
    const unsigned short* __restrict__ Abase,
    const unsigned short* __restrict__ Bbase,
    int ld, int nt,
    unsigned short* As0, unsigned short* Bs0,   // each [3][BM*BK]
    f32x4 acc[4][4], int wr, int wc, int fr, int fq)
{
    const int BUF = BM * BK;   // 8192 shorts
    int sw = fr & 7;

    // prologue: tiles 0 and 1
    stage64(Abase, ld, As0);
    stage64(Bbase, ld, Bs0);
    stage64(Abase + BK, ld, As0 + BUF);
    stage64(Bbase + BK, ld, Bs0 + BUF);

    int cur = 0;
    for (int t = 0; t < nt; ++t) {
        int nxt2 = cur + 2; if (nxt2 >= 3) nxt2 -= 3;
        if (t + 2 < nt) {
            stage64(Abase + (size_t)(t + 2) * BK, ld, As0 + nxt2 * BUF);
            stage64(Bbase + (size_t)(t + 2) * BK, ld, Bs0 + nxt2 * BUF);
            asm volatile("s_waitcnt vmcnt(16)" ::: "memory");
        } else if (t + 1 < nt) {
            asm volatile("s_waitcnt vmcnt(8)" ::: "memory");
        } else {
            asm volatile("s_waitcnt vmcnt(0)" ::: "memory");
        }
        __builtin_amdgcn_s_barrier();      // tile t visible to all waves
        asm volatile("" ::: "memory");     // compiler fence: no ds_read hoist above barrier

        const unsigned short* A = As0 + cur * BUF;
        const unsigned short* B = Bs0 + cur * BUF;
        short8 a[2][4], b[2][4];
#pragma unroll
        for (int ks = 0; ks < 2; ++ks) {
            int kc = ks * 4 + fq;
#pragma unroll
            for (int m = 0; m < 4; ++m) {
                int row = wr + m * 16 + fr;
                a[ks][m] = *reinterpret_cast<const short8*>(&A[((row << 3) + (kc ^ sw)) << 3]);
            }
#pragma unroll
            for (int n = 0; n < 4; ++n) {
                int row = wc + n * 16 + fr;
                b[ks][n] = *reinterpret_cast<const short8*>(&B[((row << 3) + (kc ^ sw)) << 3]);
            }
        }
        __builtin_amdgcn_s_setprio(1);
#pragma unroll
        for (int ks = 0; ks < 2; ++ks)
#pragma unroll
            for (int m = 0; m < 4; ++m)
#pragma unroll
                for (int n = 0; n < 4; ++n)
                    acc[m][n] = __builtin_amdgcn_mfma_f32_16x16x32_bf16(
                        a[ks][m], b[ks][n], acc[m][n], 0, 0, 0);
        __builtin_amdgcn_s_setprio(0);
        asm volatile("s_waitcnt lgkmcnt(0)" ::: "memory");  // my reads of buf[cur] done
        __builtin_amdgcn_s_barrier();                        // everyone done reading buf[cur]
        asm volatile("" ::: "memory");     // no stage-write hoist above barrier
        cur = cur + 1; if (cur >= 3) cur = 0;
    }
}

// ---------------- GEMM1: H1 = gelu(Xe @ w1^T + b1), bf16 out ----------------
// grid (GX, 24, 8); XCD-chunked remap puts all of expert z's panels on XCD z.
__global__ __launch_bounds__(256, 1) void gemm1_kernel(
    const unsigned short* __restrict__ Xe, const unsigned short* __restrict__ W1b,
    const float* __restrict__ b1, unsigned short* __restrict__ H1,
    const int* __restrict__ offs)
{
    int b = blockIdx.x + GX * (blockIdx.y + 24 * blockIdx.z);
    int l = (b & 7) * (GX * 24 * 8 / 8) + (b >> 3);   // chunked bijective swizzle
    int bx = l & (GX - 1);
    int yz = l / GX;
    int by = yz % 24;
    int e  = yz / 24;

    int segbase = offs[e];
    int segcnt = offs[e + 1] - segbase;
    if (bx * BM >= segcnt) return;
    int rowbase = segbase + bx * BM;
    int colbase = by * BN;
    const unsigned short* Abase = Xe + (size_t)rowbase * DD;
    const unsigned short* Bbase = W1b + (size_t)e * HH * DD + (size_t)colbase * DD;

    __shared__ unsigned short As[3][BM * BK];
    __shared__ unsigned short Bs[3][BN * BK];

    int tid = threadIdx.x, lane = tid & 63, w = tid >> 6;
    int wr = (w >> 1) * 64, wc = (w & 1) * 64;
    int fr = lane & 15, fq = lane >> 4;

    f32x4 acc[4][4];
#pragma unroll
    for (int m = 0; m < 4; ++m)
#pragma unroll
        for (int n = 0; n < 4; ++n) acc[m][n] = (f32x4){0.f, 0.f, 0.f, 0.f};

    gemm_core(Abase, Bbase, DD, DD / BK, &As[0][0], &Bs[0][0], acc, wr, wc, fr, fq);

#pragma unroll
    for (int m = 0; m < 4; ++m) {
        int row0 = rowbase + wr + m * 16 + fq * 4;
#pragma unroll
        for (int n = 0; n < 4; ++n) {
            int col = colbase + wc + n * 16 + fr;
            float bb = b1[e * HH + col];
#pragma unroll
            for (int r = 0; r < 4; ++r) {
                float v = acc[m][n][r] + bb;
                v = 0.5f * v * (1.f + erff(v * 0.70710678118f));
                H1[(size_t)(row0 + r) * HH + col] = f2bf(v);
            }
        }
    }
}

// ---------------- GEMM2: Yb = wpos * (H1 @ w2^T + b2), f32 out ----------------
// grid (GX, 6, 8); same chunked remap -> expert z on XCD z.
__global__ __launch_bounds__(256, 1) void gemm2_kernel(
    const unsigned short* __restrict__ H1, const unsigned short* __restrict__ W2b,
    const float* __restrict__ b2, const float* __restrict__ wpos,
    float* __restrict__ Yb, const int* __restrict__ offs)
{
    int b = blockIdx.x + GX * (blockIdx.y + 6 * blockIdx.z);
    int l = (b & 7) * (GX * 6 * 8 / 8) + (b >> 3);
    int bx = l & (GX - 1);
    int yz = l / GX;
    int by = yz % 6;
    int e  = yz / 6;

    int segbase = offs[e];
    int segcnt = offs[e + 1] - segbase;
    if (bx * BM >= segcnt) return;
    int rowbase = segbase + bx * BM;
    int colbase = by * BN;
    const unsigned short* Abase = H1 + (size_t)rowbase * HH;
    const unsigned short* Bbase = W2b + (size_t)e * DD * HH + (size_t)colbase * HH;

    __shared__ unsigned short As[3][BM * BK];
    __shared__ unsigned short Bs[3][BN * BK];

    int tid = threadIdx.x, lane = tid & 63, w = tid >> 6;
    int wr = (w >> 1) * 64, wc = (w & 1) * 64;
    int fr = lane & 15, fq = lane >> 4;

    f32x4 acc[4][4];
#pragma unroll
    for (int m = 0; m < 4; ++m)
#pragma unroll
        for (int n = 0; n < 4; ++n) acc[m][n] = (f32x4){0.f, 0.f, 0.f, 0.f};

    gemm_core(Abase, Bbase, HH, HH / BK, &As[0][0], &Bs[0][0], acc, wr, wc, fr, fq);

#pragma unroll
    for (int m = 0; m < 4; ++m) {
        int row0 = rowbase + wr + m * 16 + fq * 4;
#pragma unroll
        for (int n = 0; n < 4; ++n) {
            int col = colbase + wc + n * 16 + fr;
            float bb = b2[e * DD + col];
#pragma unroll
            for (int r = 0; r < 4; ++r) {
                float v = acc[m][n][r] + bb;
                Yb[(size_t)(row0 + r) * DD + col] = wpos[row0 + r] * v;
            }
        }
    }
}

// ---------------- combine: out[t] = Yb[pos0] + Yb[pos1]; bias passthrough ----------------
__global__ __launch_bounds__(256) void combine_kernel(
    const float* __restrict__ Yb, const int* __restrict__ pos_of,
    const float* __restrict__ bias, float* __restrict__ out, int T)
{
    int i = blockIdx.x * blockDim.x + threadIdx.x;
    int total = T * (DD / 4);
    if (i < total) {
        int t = i / (DD / 4);
        int c = (i % (DD / 4)) * 4;
        int p0 = pos_of[2 * t], p1 = pos_of[2 * t + 1];
        float4 v0 = *reinterpret_cast<const float4*>(&Yb[(size_t)p0 * DD + c]);
        float4 v1 = *reinterpret_cast<const float4*>(&Yb[(size_t)p1 * DD + c]);
        float4 o;
        o.x = v0.x + v1.x; o.y = v0.y + v1.y; o.z = v0.z + v1.z; o.w = v0.w + v1.w;
        *reinterpret_cast<float4*>(&out[(size_t)t * DD + c]) = o;
    } else if (i < total + DD / 4) {
        int c = (i - total) * 4;
        *reinterpret_cast<float4*>(&out[(size_t)T * DD + c]) =
            *reinterpret_cast<const float4*>(&bias[c]);
    }
}

extern "C" void kernel_launch(void* const* d_in, const int* in_sizes, int n_in,
                              void* d_out, int out_size, void* d_ws, size_t ws_size,
                              hipStream_t stream)
{
    const float* x    = (const float*)d_in[0];
    const float* gw   = (const float*)d_in[1];
    const float* gb   = (const float*)d_in[2];
    const float* w1   = (const float*)d_in[3];
    const float* b1   = (const float*)d_in[4];
    const float* w2   = (const float*)d_in[5];
    const float* b2   = (const float*)d_in[6];
    const float* bias = (const float*)d_in[7];
    float* out = (float*)d_out;

    int T = in_sizes[0] / DD;
    int nA = T * TOPK;
    int maxP = nA + NE * 128;

    char* ws = (char*)d_ws;
    size_t off = 0;
    auto alloc = [&](size_t bytes) -> char* {
        char* p = ws + off;
        off += (bytes + 255) & ~(size_t)255;
        return p;
    };
    unsigned short* w1b = (unsigned short*)alloc((size_t)NE * HH * DD * 2);
    unsigned short* w2b = (unsigned short*)alloc((size_t)NE * DD * HH * 2);
    unsigned short* Xe  = (unsigned short*)alloc((size_t)maxP * DD * 2);
    unsigned short* H1  = (unsigned short*)alloc((size_t)maxP * HH * 2);
    float*  Yb          = (float*)alloc((size_t)maxP * DD * 4);
    int*    topk_idx    = (int*)alloc((size_t)nA * 4);
    float*  topk_w      = (float*)alloc((size_t)nA * 4);
    int*    pos_of      = (int*)alloc((size_t)nA * 4);
    float*  wpos        = (float*)alloc((size_t)maxP * 4);
    int*    token_map   = (int*)alloc((size_t)maxP * 4);
    int*    ctrl        = (int*)alloc(32 * 4);

    size_t nW = (size_t)NE * HH * DD;

    hipLaunchKernelGGL(convert_kernel, dim3(4096), dim3(256), 0, stream,
                       w1, w2, w1b, w2b, nW);
    hipLaunchKernelGGL(init_kernel, dim3((maxP + 255) / 256), dim3(256), 0, stream,
                       token_map, ctrl, maxP);
    hipLaunchKernelGGL(gate_kernel, dim3((T + 3) / 4), dim3(256), 0, stream,
                       x, gw, gb, topk_idx, topk_w, ctrl, T);
    hipLaunchKernelGGL(offsets_kernel, dim3(1), dim3(64), 0, stream, ctrl);
    hipLaunchKernelGGL(scatter_kernel, dim3((nA + 255) / 256), dim3(256), 0, stream,
                       topk_idx, topk_w, ctrl, token_map, pos_of, wpos, nA);
    hipLaunchKernelGGL(gather_kernel, dim3((maxP * (DD / 4) + 255) / 256), dim3(256), 0, stream,
                       x, token_map, Xe, maxP);
    hipLaunchKernelGGL(gemm1_kernel, dim3(GX, HH / BN, NE), dim3(256), 0, stream,
                       Xe, w1b, b1, H1, ctrl + 16);
    hipLaunchKernelGGL(gemm2_kernel, dim3(GX, DD / BN, NE), dim3(256), 0, stream,
                       H1, w2b, b2, wpos, Yb, ctrl + 16);
    hipLaunchKernelGGL(combine_kernel, dim3((T * (DD / 4) + DD / 4 + 255) / 256, 1, 1), dim3(256), 0, stream,
                       Yb, pos_of, bias, out, T);
}

// Round 3
// 457.068 us; speedup vs baseline: 1.3380x; 1.2361x over previous
//
#include <hip/hip_runtime.h>
#include <hip/hip_bf16.h>

#define DD 768
#define HH 3072
#define NE 8
#define TOPK 2

#define BM 256
#define BN 256
#define BK 64
#define GXB 8    // row-blocks of 256 per expert (capacity 2048 rows/expert)

typedef __attribute__((ext_vector_type(8))) short short8;
typedef __attribute__((ext_vector_type(4))) float f32x4;

static __device__ __forceinline__ unsigned short f2bf(float v) {
    __hip_bfloat16 b = __float2bfloat16(v);
    return *reinterpret_cast<unsigned short*>(&b);
}

// ---------------- weight conversion fp32 -> bf16 ----------------
__global__ __launch_bounds__(256) void convert_kernel(
    const float* __restrict__ w1, const float* __restrict__ w2,
    unsigned short* __restrict__ w1b, unsigned short* __restrict__ w2b, size_t n)
{
    size_t tid = (size_t)blockIdx.x * blockDim.x + threadIdx.x;
    size_t stride = (size_t)gridDim.x * blockDim.x;
    size_t quarter = n / 4;            // float4 count per tensor
    size_t tot = 2 * quarter;
    for (size_t j = tid; j < tot; j += stride) {
        const float* src; unsigned short* dst; size_t off;
        if (j < quarter) { src = w1; dst = w1b; off = j * 4; }
        else             { src = w2; dst = w2b; off = (j - quarter) * 4; }
        float4 v = *reinterpret_cast<const float4*>(&src[off]);
        ushort4 o;
        o.x = f2bf(v.x); o.y = f2bf(v.y); o.z = f2bf(v.z); o.w = f2bf(v.w);
        *reinterpret_cast<ushort4*>(&dst[off]) = o;
    }
}

// ---------------- init control block + token_map ----------------
__global__ __launch_bounds__(256) void init_kernel(int* token_map, int* ctrl, int maxP)
{
    int i = blockIdx.x * blockDim.x + threadIdx.x;
    if (i < maxP) token_map[i] = -1;
    if (i < 32) ctrl[i] = 0;   // [0..8) counts, [8..16) cursors, [16..25) offsets
}

// ---------------- gate: logits, top-2, softmax ----------------
__global__ __launch_bounds__(256) void gate_kernel(
    const float* __restrict__ x, const float* __restrict__ gw, const float* __restrict__ gb,
    int* __restrict__ topk_idx, float* __restrict__ topk_w, int* __restrict__ ctrl, int T)
{
    int t = blockIdx.x * 4 + (threadIdx.x >> 6);
    int lane = threadIdx.x & 63;
    if (t >= T) return;
    float acc[NE];
#pragma unroll
    for (int e = 0; e < NE; ++e) acc[e] = 0.f;
    const float* xr = x + (size_t)t * DD;
    for (int d = lane; d < DD; d += 64) {
        float xv = xr[d];
#pragma unroll
        for (int e = 0; e < NE; ++e) acc[e] += xv * gw[e * DD + d];
    }
#pragma unroll
    for (int e = 0; e < NE; ++e) {
        float v = acc[e];
        for (int off = 32; off; off >>= 1) v += __shfl_xor(v, off, 64);
        acc[e] = v;
    }
    if (lane == 0) {
        float lg[NE];
#pragma unroll
        for (int e = 0; e < NE; ++e) lg[e] = acc[e] + gb[e];
        int i0 = 0;
#pragma unroll
        for (int e = 1; e < NE; ++e) if (lg[e] > lg[i0]) i0 = e;
        int i1 = -1;
#pragma unroll
        for (int e = 0; e < NE; ++e) {
            if (e == i0) continue;
            if (i1 < 0 || lg[e] > lg[i1]) i1 = e;
        }
        float m = lg[i0];
        float e0 = __expf(lg[i0] - m), e1 = __expf(lg[i1] - m);
        float s = e0 + e1;
        topk_idx[2 * t]     = i0;
        topk_idx[2 * t + 1] = i1;
        topk_w[2 * t]       = e0 / s;
        topk_w[2 * t + 1]   = e1 / s;
        atomicAdd(&ctrl[i0], 1);
        atomicAdd(&ctrl[i1], 1);
    }
}

// ---------------- offsets (padded to 256 per expert) ----------------
__global__ void offsets_kernel(int* ctrl)
{
    if (threadIdx.x == 0 && blockIdx.x == 0) {
        int acc = 0;
        for (int e = 0; e < NE; ++e) {
            ctrl[16 + e] = acc;
            acc += (ctrl[e] + 255) & ~255;
        }
        ctrl[16 + NE] = acc;
    }
}

// ---------------- scatter assignments to expert segments ----------------
__global__ __launch_bounds__(256) void scatter_kernel(
    const int* __restrict__ topk_idx, const float* __restrict__ topk_w,
    int* ctrl, int* token_map, int* pos_of, float* wpos, int nA)
{
    int a = blockIdx.x * blockDim.x + threadIdx.x;
    if (a >= nA) return;
    int e = topk_idx[a];
    int p = ctrl[16 + e] + atomicAdd(&ctrl[8 + e], 1);
    token_map[p] = a;
    pos_of[a] = p;
    wpos[p] = topk_w[a];
}

// ---------------- gather x rows -> bf16 Xe ----------------
__global__ __launch_bounds__(256) void gather_kernel(
    const float* __restrict__ x, const int* __restrict__ token_map,
    unsigned short* __restrict__ Xe, int maxP)
{
    int i = blockIdx.x * blockDim.x + threadIdx.x;
    int total = maxP * (DD / 4);
    if (i >= total) return;
    int r = i / (DD / 4);
    int c = (i % (DD / 4)) * 4;
    int a = token_map[r];
    ushort4 o;
    if (a < 0) {
        o.x = o.y = o.z = o.w = 0;
    } else {
        float4 v = *reinterpret_cast<const float4*>(&x[(size_t)(a >> 1) * DD + c]);
        o.x = f2bf(v.x); o.y = f2bf(v.y); o.z = f2bf(v.z); o.w = f2bf(v.w);
    }
    *reinterpret_cast<ushort4*>(&Xe[(size_t)r * DD + c]) = o;
}

// ---------------- staging: one 128-row x 64-col quarter (16 KB) -> LDS ----------------
// Linear LDS dest + inverse-XOR-swizzled per-lane global source (verified 0 conflicts).
// Chunk (row, kc) lives at LDS chunk row*8 + (kc ^ (row&7)); reader applies same XOR.
static __device__ __forceinline__ void stage_quarter(
    const unsigned short* __restrict__ gq, int ld, unsigned short* __restrict__ ldsq)
{
    int tid = threadIdx.x;   // 0..511
#pragma unroll
    for (int r = 0; r < 2; ++r) {
        int j = (r << 9) + tid;           // chunk idx 0..1023
        int row = j >> 3;                 // 0..127
        int kc = (j & 7) ^ (row & 7);     // inverse swizzle on SOURCE
        __builtin_amdgcn_global_load_lds(
            (const __attribute__((address_space(1))) void*)(gq + (size_t)row * ld + (kc << 3)),
            (__attribute__((address_space(3))) void*)(ldsq + (j << 3)),
            16, 0, 0);
    }
}

#define LDSF(base, row, kc) \
    reinterpret_cast<const short8*>(&(base)[((((row) << 3) + ((kc) ^ ((row) & 7))) << 3)])

// ---------------- 8-wave 256x256 phase-interleaved GEMM core ----------------
// Per K-tile: 4 phases. Each phase: entry barrier -> stage one quarter of tile t+1
// (2 global_load_lds) -> ds_read frag pair -> 16 MFMA (setprio-wrapped).
// Phase 0 additionally: counted vmcnt(2) + 2nd barrier (prev tile landed everywhere;
// fresh quarter stays in flight). Loads get 1-4 phases (~600-2400 cy) of MFMA cover.
static __device__ __forceinline__ void gemm_core(
    const unsigned short* __restrict__ Abase,   // 256 rows x K
    const unsigned short* __restrict__ Bbase,   // 256 rows x K
    int ld, int nt,
    unsigned short* __restrict__ As, unsigned short* __restrict__ Bs, // [2][16384] each
    f32x4 acc[8][4], int wm, int wn, int fr, int fq)
{
    const int TQ = 8192;     // shorts per quarter
    const int TB = 16384;    // shorts per tile buffer

    // prologue: tile 0 -> buf 0 (8 loads/thread; waited by p0's vmcnt of t=0)
    stage_quarter(Abase,                 ld, As);
    stage_quarter(Abase + (size_t)128 * ld, ld, As + TQ);
    stage_quarter(Bbase,                 ld, Bs);
    stage_quarter(Bbase + (size_t)128 * ld, ld, Bs + TQ);

    int arow0 = wm * 128 + fr;
    int brow0 = wn * 64 + fr;

    for (int t = 0; t < nt; ++t) {
        int cur = t & 1;
        const unsigned short* A = As + cur * TB;
        const unsigned short* B = Bs + cur * TB;
        unsigned short* An = As + (cur ^ 1) * TB;
        unsigned short* Bn = Bs + (cur ^ 1) * TB;
        const unsigned short* Ag = Abase + (size_t)(t + 1) * BK;
        const unsigned short* Bg = Bbase + (size_t)(t + 1) * BK;
        bool pf = (t + 1 < nt);

        short8 b[2][4];

        // ---------- phase 0 : stage A-lo(t+1); compute m=0,1 ----------
        __builtin_amdgcn_s_barrier();
        asm volatile("" ::: "memory");
        if (pf) stage_quarter(Ag, ld, An);
        if (pf) asm volatile("s_waitcnt vmcnt(2)" ::: "memory");
        else    asm volatile("s_waitcnt vmcnt(0)" ::: "memory");
        __builtin_amdgcn_s_barrier();
        asm volatile("" ::: "memory");
        {
#pragma unroll
            for (int ks = 0; ks < 2; ++ks) {
                int kc = ks * 4 + fq;
#pragma unroll
                for (int n = 0; n < 4; ++n)
                    b[ks][n] = *LDSF(B, brow0 + n * 16, kc);
            }
            short8 a0[2][2];
#pragma unroll
            for (int ks = 0; ks < 2; ++ks) {
                int kc = ks * 4 + fq;
                a0[ks][0] = *LDSF(A, arow0 + 0 * 16, kc);
                a0[ks][1] = *LDSF(A, arow0 + 1 * 16, kc);
            }
            __builtin_amdgcn_s_setprio(1);
#pragma unroll
            for (int ks = 0; ks < 2; ++ks)
#pragma unroll
                for (int mi = 0; mi < 2; ++mi)
#pragma unroll
                    for (int n = 0; n < 4; ++n)
                        acc[mi][n] = __builtin_amdgcn_mfma_f32_16x16x32_bf16(
                            a0[ks][mi], b[ks][n], acc[mi][n], 0, 0, 0);
            __builtin_amdgcn_s_setprio(0);
        }

        // ---------- phases 1..3 : stage A-hi / B-lo / B-hi; compute m=2p..2p+1 ----------
#pragma unroll
        for (int p = 1; p < 4; ++p) {
            __builtin_amdgcn_s_barrier();
            asm volatile("" ::: "memory");
            if (pf) {
                if (p == 1) stage_quarter(Ag + (size_t)128 * ld, ld, An + TQ);
                if (p == 2) stage_quarter(Bg,                    ld, Bn);
                if (p == 3) stage_quarter(Bg + (size_t)128 * ld, ld, Bn + TQ);
            }
            short8 ap[2][2];
#pragma unroll
            for (int ks = 0; ks < 2; ++ks) {
                int kc = ks * 4 + fq;
                ap[ks][0] = *LDSF(A, arow0 + (2 * p + 0) * 16, kc);
                ap[ks][1] = *LDSF(A, arow0 + (2 * p + 1) * 16, kc);
            }
            __builtin_amdgcn_s_setprio(1);
#pragma unroll
            for (int ks = 0; ks < 2; ++ks)
#pragma unroll
                for (int mi = 0; mi < 2; ++mi)
#pragma unroll
                    for (int n = 0; n < 4; ++n)
                        acc[2 * p + mi][n] = __builtin_amdgcn_mfma_f32_16x16x32_bf16(
                            ap[ks][mi], b[ks][n], acc[2 * p + mi][n], 0, 0, 0);
            __builtin_amdgcn_s_setprio(0);
        }
    }
}

// ---------------- GEMM1: H1 = gelu(Xe @ w1^T + b1), bf16 out ----------------
__global__ __launch_bounds__(512, 2) void gemm1_kernel(
    const unsigned short* __restrict__ Xe, const unsigned short* __restrict__ W1b,
    const float* __restrict__ b1, unsigned short* __restrict__ H1,
    const int* __restrict__ offs)
{
    int e = blockIdx.z;
    int segbase = offs[e];
    int segcnt = offs[e + 1] - segbase;
    if ((int)blockIdx.x * BM >= segcnt) return;
    int rowbase = segbase + blockIdx.x * BM;
    int colbase = blockIdx.y * BN;
    const unsigned short* Abase = Xe + (size_t)rowbase * DD;
    const unsigned short* Bbase = W1b + (size_t)e * HH * DD + (size_t)colbase * DD;

    __shared__ unsigned short As[2 * 16384];
    __shared__ unsigned short Bs[2 * 16384];

    int tid = threadIdx.x, lane = tid & 63, w = tid >> 6;
    int wm = w >> 2, wn = w & 3;
    int fr = lane & 15, fq = lane >> 4;

    f32x4 acc[8][4];
#pragma unroll
    for (int m = 0; m < 8; ++m)
#pragma unroll
        for (int n = 0; n < 4; ++n) acc[m][n] = (f32x4){0.f, 0.f, 0.f, 0.f};

    gemm_core(Abase, Bbase, DD, DD / BK, As, Bs, acc, wm, wn, fr, fq);

    float bb[4];
#pragma unroll
    for (int n = 0; n < 4; ++n)
        bb[n] = b1[e * HH + colbase + wn * 64 + n * 16 + fr];

#pragma unroll
    for (int m = 0; m < 8; ++m) {
        int row0 = rowbase + wm * 128 + m * 16 + fq * 4;
#pragma unroll
        for (int n = 0; n < 4; ++n) {
            int col = colbase + wn * 64 + n * 16 + fr;
#pragma unroll
            for (int r = 0; r < 4; ++r) {
                float v = acc[m][n][r] + bb[n];
                v = 0.5f * v * (1.f + erff(v * 0.70710678118f));
                H1[(size_t)(row0 + r) * HH + col] = f2bf(v);
            }
        }
    }
}

// ---------------- GEMM2: Yb = wpos * (H1 @ w2^T + b2), f32 out ----------------
__global__ __launch_bounds__(512, 2) void gemm2_kernel(
    const unsigned short* __restrict__ H1, const unsigned short* __restrict__ W2b,
    const float* __restrict__ b2, const float* __restrict__ wpos,
    float* __restrict__ Yb, const int* __restrict__ offs)
{
    int e = blockIdx.z;
    int segbase = offs[e];
    int segcnt = offs[e + 1] - segbase;
    if ((int)blockIdx.x * BM >= segcnt) return;
    int rowbase = segbase + blockIdx.x * BM;
    int colbase = blockIdx.y * BN;
    const unsigned short* Abase = H1 + (size_t)rowbase * HH;
    const unsigned short* Bbase = W2b + (size_t)e * DD * HH + (size_t)colbase * HH;

    __shared__ unsigned short As[2 * 16384];
    __shared__ unsigned short Bs[2 * 16384];

    int tid = threadIdx.x, lane = tid & 63, w = tid >> 6;
    int wm = w >> 2, wn = w & 3;
    int fr = lane & 15, fq = lane >> 4;

    f32x4 acc[8][4];
#pragma unroll
    for (int m = 0; m < 8; ++m)
#pragma unroll
        for (int n = 0; n < 4; ++n) acc[m][n] = (f32x4){0.f, 0.f, 0.f, 0.f};

    gemm_core(Abase, Bbase, HH, HH / BK, As, Bs, acc, wm, wn, fr, fq);

    float bb[4];
#pragma unroll
    for (int n = 0; n < 4; ++n)
        bb[n] = b2[e * DD + colbase + wn * 64 + n * 16 + fr];

#pragma unroll
    for (int m = 0; m < 8; ++m) {
        int row0 = rowbase + wm * 128 + m * 16 + fq * 4;
        float wp[4];
#pragma unroll
        for (int r = 0; r < 4; ++r) wp[r] = wpos[row0 + r];
#pragma unroll
        for (int n = 0; n < 4; ++n) {
            int col = colbase + wn * 64 + n * 16 + fr;
#pragma unroll
            for (int r = 0; r < 4; ++r) {
                float v = acc[m][n][r] + bb[n];
                Yb[(size_t)(row0 + r) * DD + col] = wp[r] * v;
            }
        }
    }
}

// ---------------- combine: out[t] = Yb[pos0] + Yb[pos1]; bias passthrough ----------------
__global__ __launch_bounds__(256) void combine_kernel(
    const float* __restrict__ Yb, const int* __restrict__ pos_of,
    const float* __restrict__ bias, float* __restrict__ out, int T)
{
    int i = blockIdx.x * blockDim.x + threadIdx.x;
    int total = T * (DD / 4);
    if (i < total) {
        int t = i / (DD / 4);
        int c = (i % (DD / 4)) * 4;
        int p0 = pos_of[2 * t], p1 = pos_of[2 * t + 1];
        float4 v0 = *reinterpret_cast<const float4*>(&Yb[(size_t)p0 * DD + c]);
        float4 v1 = *reinterpret_cast<const float4*>(&Yb[(size_t)p1 * DD + c]);
        float4 o;
        o.x = v0.x + v1.x; o.y = v0.y + v1.y; o.z = v0.z + v1.z; o.w = v0.w + v1.w;
        *reinterpret_cast<float4*>(&out[(size_t)t * DD + c]) = o;
    } else if (i < total + DD / 4) {
        int c = (i - total) * 4;
        *reinterpret_cast<float4*>(&out[(size_t)T * DD + c]) =
            *reinterpret_cast<const float4*>(&bias[c]);
    }
}

extern "C" void kernel_launch(void* const* d_in, const int* in_sizes, int n_in,
                              void* d_out, int out_size, void* d_ws, size_t ws_size,
                              hipStream_t stream)
{
    const float* x    = (const float*)d_in[0];
    const float* gw   = (const float*)d_in[1];
    const float* gb   = (const float*)d_in[2];
    const float* w1   = (const float*)d_in[3];
    const float* b1   = (const float*)d_in[4];
    const float* w2   = (const float*)d_in[5];
    const float* b2   = (const float*)d_in[6];
    const float* bias = (const float*)d_in[7];
    float* out = (float*)d_out;

    int T = in_sizes[0] / DD;
    int nA = T * TOPK;
    int maxP = nA + NE * 256;

    char* ws = (char*)d_ws;
    size_t off = 0;
    auto alloc = [&](size_t bytes) -> char* {
        char* p = ws + off;
        off += (bytes + 255) & ~(size_t)255;
        return p;
    };
    unsigned short* w1b = (unsigned short*)alloc((size_t)NE * HH * DD * 2);
    unsigned short* w2b = (unsigned short*)alloc((size_t)NE * DD * HH * 2);
    unsigned short* Xe  = (unsigned short*)alloc((size_t)maxP * DD * 2);
    unsigned short* H1  = (unsigned short*)alloc((size_t)maxP * HH * 2);
    float*  Yb          = (float*)alloc((size_t)maxP * DD * 4);
    int*    topk_idx    = (int*)alloc((size_t)nA * 4);
    float*  topk_w      = (float*)alloc((size_t)nA * 4);
    int*    pos_of      = (int*)alloc((size_t)nA * 4);
    float*  wpos        = (float*)alloc((size_t)maxP * 4);
    int*    token_map   = (int*)alloc((size_t)maxP * 4);
    int*    ctrl        = (int*)alloc(32 * 4);

    size_t nW = (size_t)NE * HH * DD;

    hipLaunchKernelGGL(convert_kernel, dim3(4096), dim3(256), 0, stream,
                       w1, w2, w1b, w2b, nW);
    hipLaunchKernelGGL(init_kernel, dim3((maxP + 255) / 256), dim3(256), 0, stream,
                       token_map, ctrl, maxP);
    hipLaunchKernelGGL(gate_kernel, dim3((T + 3) / 4), dim3(256), 0, stream,
                       x, gw, gb, topk_idx, topk_w, ctrl, T);
    hipLaunchKernelGGL(offsets_kernel, dim3(1), dim3(64), 0, stream, ctrl);
    hipLaunchKernelGGL(scatter_kernel, dim3((nA + 255) / 256), dim3(256), 0, stream,
                       topk_idx, topk_w, ctrl, token_map, pos_of, wpos, nA);
    hipLaunchKernelGGL(gather_kernel, dim3((maxP * (DD / 4) + 255) / 256), dim3(256), 0, stream,
                       x, token_map, Xe, maxP);
    hipLaunchKernelGGL(gemm1_kernel, dim3(GXB, HH / BN, NE), dim3(512), 0, stream,
                       Xe, w1b, b1, H1, ctrl + 16);
    hipLaunchKernelGGL(gemm2_kernel, dim3(GXB, DD / BN, NE), dim3(512), 0, stream,
                       H1, w2b, b2, wpos, Yb, ctrl + 16);
    hipLaunchKernelGGL(combine_kernel, dim3((T * (DD / 4) + DD / 4 + 255) / 256, 1, 1), dim3(256), 0, stream,
                       Yb, pos_of, bias, out, T);
}

// Round 4
// 373.541 us; speedup vs baseline: 1.6371x; 1.2236x over previous
//
#include <hip/hip_runtime.h>
#include <hip/hip_bf16.h>

#define DD 768
#define HH 3072
#define NE 8
#define TOPK 2

#define BK 64
#define NB1 (HH / 128)   // 24 col blocks, gemm1
#define NB2 (DD / 128)   // 6 col blocks, gemm2

typedef __attribute__((ext_vector_type(8))) short short8;
typedef __attribute__((ext_vector_type(4))) float f32x4;

static __device__ __forceinline__ unsigned short f2bf(float v) {
    __hip_bfloat16 b = __float2bfloat16(v);
    return *reinterpret_cast<unsigned short*>(&b);
}

// ---------------- weight conversion fp32 -> bf16 ----------------
__global__ __launch_bounds__(256) void convert_kernel(
    const float* __restrict__ w1, const float* __restrict__ w2,
    unsigned short* __restrict__ w1b, unsigned short* __restrict__ w2b, size_t n)
{
    size_t tid = (size_t)blockIdx.x * blockDim.x + threadIdx.x;
    size_t stride = (size_t)gridDim.x * blockDim.x;
    size_t quarter = n / 4;            // float4 count per tensor
    size_t tot = 2 * quarter;
    for (size_t j = tid; j < tot; j += stride) {
        const float* src; unsigned short* dst; size_t off;
        if (j < quarter) { src = w1; dst = w1b; off = j * 4; }
        else             { src = w2; dst = w2b; off = (j - quarter) * 4; }
        float4 v = *reinterpret_cast<const float4*>(&src[off]);
        ushort4 o;
        o.x = f2bf(v.x); o.y = f2bf(v.y); o.z = f2bf(v.z); o.w = f2bf(v.w);
        *reinterpret_cast<ushort4*>(&dst[off]) = o;
    }
}

// ---------------- init control block + token_map ----------------
// ctrl: [0..8) counts | [8..16) scatter cursors | [16..25) row offsets |
//       [26] g1 item cursor | [27] g2 item cursor |
//       [32..41) g1 item prefix | [41..50) g2 item prefix
__global__ __launch_bounds__(256) void init_kernel(int* token_map, int* ctrl, int maxP)
{
    int i = blockIdx.x * blockDim.x + threadIdx.x;
    if (i < maxP) token_map[i] = -1;
    if (i < 64) ctrl[i] = 0;
}

// ---------------- gate: logits, top-2, softmax ----------------
__global__ __launch_bounds__(256) void gate_kernel(
    const float* __restrict__ x, const float* __restrict__ gw, const float* __restrict__ gb,
    int* __restrict__ topk_idx, float* __restrict__ topk_w, int* __restrict__ ctrl, int T)
{
    int t = blockIdx.x * 4 + (threadIdx.x >> 6);
    int lane = threadIdx.x & 63;
    if (t >= T) return;
    float acc[NE];
#pragma unroll
    for (int e = 0; e < NE; ++e) acc[e] = 0.f;
    const float* xr = x + (size_t)t * DD;
    for (int d = lane; d < DD; d += 64) {
        float xv = xr[d];
#pragma unroll
        for (int e = 0; e < NE; ++e) acc[e] += xv * gw[e * DD + d];
    }
#pragma unroll
    for (int e = 0; e < NE; ++e) {
        float v = acc[e];
        for (int off = 32; off; off >>= 1) v += __shfl_xor(v, off, 64);
        acc[e] = v;
    }
    if (lane == 0) {
        float lg[NE];
#pragma unroll
        for (int e = 0; e < NE; ++e) lg[e] = acc[e] + gb[e];
        int i0 = 0;
#pragma unroll
        for (int e = 1; e < NE; ++e) if (lg[e] > lg[i0]) i0 = e;
        int i1 = -1;
#pragma unroll
        for (int e = 0; e < NE; ++e) {
            if (e == i0) continue;
            if (i1 < 0 || lg[e] > lg[i1]) i1 = e;
        }
        float m = lg[i0];
        float e0 = __expf(lg[i0] - m), e1 = __expf(lg[i1] - m);
        float s = e0 + e1;
        topk_idx[2 * t]     = i0;
        topk_idx[2 * t + 1] = i1;
        topk_w[2 * t]       = e0 / s;
        topk_w[2 * t + 1]   = e1 / s;
        atomicAdd(&ctrl[i0], 1);
        atomicAdd(&ctrl[i1], 1);
    }
}

// ---------------- offsets + work-item enumeration ----------------
__global__ void offsets_kernel(int* ctrl)
{
    if (threadIdx.x == 0 && blockIdx.x == 0) {
        int acc = 0, it1 = 0, it2 = 0;
        for (int e = 0; e < NE; ++e) {
            ctrl[16 + e] = acc;
            int nrb = (ctrl[e] + 127) >> 7;        // active 128-row blocks
            acc += nrb << 7;
            ctrl[32 + e] = it1; it1 += nrb * NB1;
            ctrl[41 + e] = it2; it2 += nrb * NB2;
        }
        ctrl[24] = acc;      // total padded rows
        ctrl[40] = it1;      // total gemm1 items
        ctrl[49] = it2;      // total gemm2 items
    }
}

// ---------------- scatter assignments to expert segments ----------------
__global__ __launch_bounds__(256) void scatter_kernel(
    const int* __restrict__ topk_idx, const float* __restrict__ topk_w,
    int* ctrl, int* token_map, int* pos_of, float* wpos, int nA)
{
    int a = blockIdx.x * blockDim.x + threadIdx.x;
    if (a >= nA) return;
    int e = topk_idx[a];
    int p = ctrl[16 + e] + atomicAdd(&ctrl[8 + e], 1);
    token_map[p] = a;
    pos_of[a] = p;
    wpos[p] = topk_w[a];
}

// ---------------- gather x rows -> bf16 Xe ----------------
__global__ __launch_bounds__(256) void gather_kernel(
    const float* __restrict__ x, const int* __restrict__ token_map,
    unsigned short* __restrict__ Xe, int maxP)
{
    int i = blockIdx.x * blockDim.x + threadIdx.x;
    int total = maxP * (DD / 4);
    if (i >= total) return;
    int r = i / (DD / 4);
    int c = (i % (DD / 4)) * 4;
    int a = token_map[r];
    ushort4 o;
    if (a < 0) {
        o.x = o.y = o.z = o.w = 0;
    } else {
        float4 v = *reinterpret_cast<const float4*>(&x[(size_t)(a >> 1) * DD + c]);
        o.x = f2bf(v.x); o.y = f2bf(v.y); o.z = f2bf(v.z); o.w = f2bf(v.w);
    }
    *reinterpret_cast<ushort4*>(&Xe[(size_t)r * DD + c]) = o;
}

// ---------------- staging: 128 rows x 64 cols bf16 tile -> LDS ----------------
// Linear LDS dest + inverse-XOR-swizzled per-lane global source (verified: 0 conflicts).
// Chunk (row,kc) lives at LDS chunk row*8 + (kc ^ (row&7)); reader applies same XOR.
static __device__ __forceinline__ void stage_tile(
    const unsigned short* __restrict__ g, int ld, unsigned short* __restrict__ lds)
{
    int tid = threadIdx.x;   // 256 threads, 4 chunks each
#pragma unroll
    for (int r = 0; r < 4; ++r) {
        int j = (r << 8) + tid;           // chunk idx 0..1023
        int row = j >> 3;
        int kc = (j & 7) ^ (row & 7);     // inverse swizzle on SOURCE
        __builtin_amdgcn_global_load_lds(
            (const __attribute__((address_space(1))) void*)(g + (size_t)row * ld + (kc << 3)),
            (__attribute__((address_space(3))) void*)(lds + (j << 3)),
            16, 0, 0);
    }
}

#define LDSF(base, row, kc) \
    reinterpret_cast<const short8*>(&(base)[((((row) << 3) + ((kc) ^ ((row) & 7))) << 3)])

// ---------------- minimum-2-phase dbuf K-loop (catalog-verified pattern) ----------------
// Per K-tile: issue stage(t+1) into alt buffer FIRST, ds_read current, 32 MFMA,
// then ONE __syncthreads (vmcnt+lgkm drain) per tile. Stage latency hides under
// the MFMA phase; cross-block TLP (2 blocks/CU) covers the barrier.
static __device__ __forceinline__ void gemm_item(
    const unsigned short* __restrict__ Abase,
    const unsigned short* __restrict__ Bbase,
    int ld, int nt,
    unsigned short* __restrict__ As, unsigned short* __restrict__ Bs, // each [2][8192]
    f32x4 acc[4][4], int wr, int wc, int fr, int fq)
{
    const int BUF = 128 * 64;
    stage_tile(Abase, ld, As);
    stage_tile(Bbase, ld, Bs);
    __syncthreads();
    for (int t = 0; t < nt; ++t) {
        int cur = t & 1;
        if (t + 1 < nt) {
            stage_tile(Abase + (size_t)(t + 1) * BK, ld, As + (cur ^ 1) * BUF);
            stage_tile(Bbase + (size_t)(t + 1) * BK, ld, Bs + (cur ^ 1) * BUF);
        }
        const unsigned short* A = As + cur * BUF;
        const unsigned short* B = Bs + cur * BUF;
        short8 a[2][4], b[2][4];
#pragma unroll
        for (int ks = 0; ks < 2; ++ks) {
            int kc = ks * 4 + fq;
#pragma unroll
            for (int m = 0; m < 4; ++m)
                a[ks][m] = *LDSF(A, wr + m * 16 + fr, kc);
#pragma unroll
            for (int n = 0; n < 4; ++n)
                b[ks][n] = *LDSF(B, wc + n * 16 + fr, kc);
        }
        __builtin_amdgcn_s_setprio(1);
#pragma unroll
        for (int ks = 0; ks < 2; ++ks)
#pragma unroll
            for (int m = 0; m < 4; ++m)
#pragma unroll
                for (int n = 0; n < 4; ++n)
                    acc[m][n] = __builtin_amdgcn_mfma_f32_16x16x32_bf16(
                        a[ks][m], b[ks][n], acc[m][n], 0, 0, 0);
        __builtin_amdgcn_s_setprio(0);
        __syncthreads();
    }
}

// ---------------- GEMM1: persistent work-queue, H1 = gelu(Xe@w1^T+b1) ----------------
__global__ __launch_bounds__(256, 2) void gemm1_kernel(
    const unsigned short* __restrict__ Xe, const unsigned short* __restrict__ W1b,
    const float* __restrict__ b1, unsigned short* __restrict__ H1,
    int* __restrict__ ctrl)
{
    __shared__ unsigned short As[2 * 128 * 64];
    __shared__ unsigned short Bs[2 * 128 * 64];
    __shared__ int sh_item;

    int tid = threadIdx.x, lane = tid & 63, w = tid >> 6;
    int wr = (w >> 1) * 64, wc = (w & 1) * 64;
    int fr = lane & 15, fq = lane >> 4;
    int tot = ctrl[40];

    for (;;) {
        if (tid == 0) sh_item = atomicAdd(&ctrl[26], 1);
        __syncthreads();
        int item = sh_item;
        if (item >= tot) return;

        // decode item -> (expert e, col block cb, row block rb); rb fast so
        // consecutive poppers share the same B panel (L2/L3 broadcast).
        int e = 7;
        while (item < ctrl[32 + e]) --e;
        int loc = item - ctrl[32 + e];
        int segbase = ctrl[16 + e];
        int nrb = (ctrl[17 + e] - segbase) >> 7;
        int cb = loc / nrb;
        int rb = loc - cb * nrb;
        int rowbase = segbase + (rb << 7);
        int colbase = cb << 7;

        const unsigned short* Abase = Xe + (size_t)rowbase * DD;
        const unsigned short* Bbase = W1b + (size_t)e * HH * DD + (size_t)colbase * DD;

        f32x4 acc[4][4];
#pragma unroll
        for (int m = 0; m < 4; ++m)
#pragma unroll
            for (int n = 0; n < 4; ++n) acc[m][n] = (f32x4){0.f, 0.f, 0.f, 0.f};

        gemm_item(Abase, Bbase, DD, DD / BK, As, Bs, acc, wr, wc, fr, fq);

#pragma unroll
        for (int m = 0; m < 4; ++m) {
            int row0 = rowbase + wr + m * 16 + fq * 4;
#pragma unroll
            for (int n = 0; n < 4; ++n) {
                int col = colbase + wc + n * 16 + fr;
                float bb = b1[e * HH + col];
#pragma unroll
                for (int r = 0; r < 4; ++r) {
                    float v = acc[m][n][r] + bb;
                    v = 0.5f * v * (1.f + erff(v * 0.70710678118f));
                    H1[(size_t)(row0 + r) * HH + col] = f2bf(v);
                }
            }
        }
    }
}

// ---------------- GEMM2: persistent work-queue, Yb = wpos*(H1@w2^T+b2) ----------------
__global__ __launch_bounds__(256, 2) void gemm2_kernel(
    const unsigned short* __restrict__ H1, const unsigned short* __restrict__ W2b,
    const float* __restrict__ b2, const float* __restrict__ wpos,
    float* __restrict__ Yb, int* __restrict__ ctrl)
{
    __shared__ unsigned short As[2 * 128 * 64];
    __shared__ unsigned short Bs[2 * 128 * 64];
    __shared__ int sh_item;

    int tid = threadIdx.x, lane = tid & 63, w = tid >> 6;
    int wr = (w >> 1) * 64, wc = (w & 1) * 64;
    int fr = lane & 15, fq = lane >> 4;
    int tot = ctrl[49];

    for (;;) {
        if (tid == 0) sh_item = atomicAdd(&ctrl[27], 1);
        __syncthreads();
        int item = sh_item;
        if (item >= tot) return;

        int e = 7;
        while (item < ctrl[41 + e]) --e;
        int loc = item - ctrl[41 + e];
        int segbase = ctrl[16 + e];
        int nrb = (ctrl[17 + e] - segbase) >> 7;
        int cb = loc / nrb;
        int rb = loc - cb * nrb;
        int rowbase = segbase + (rb << 7);
        int colbase = cb << 7;

        const unsigned short* Abase = H1 + (size_t)rowbase * HH;
        const unsigned short* Bbase = W2b + (size_t)e * DD * HH + (size_t)colbase * HH;

        f32x4 acc[4][4];
#pragma unroll
        for (int m = 0; m < 4; ++m)
#pragma unroll
            for (int n = 0; n < 4; ++n) acc[m][n] = (f32x4){0.f, 0.f, 0.f, 0.f};

        gemm_item(Abase, Bbase, HH, HH / BK, As, Bs, acc, wr, wc, fr, fq);

#pragma unroll
        for (int m = 0; m < 4; ++m) {
            int row0 = rowbase + wr + m * 16 + fq * 4;
            float wp[4];
#pragma unroll
            for (int r = 0; r < 4; ++r) wp[r] = wpos[row0 + r];
#pragma unroll
            for (int n = 0; n < 4; ++n) {
                int col = colbase + wc + n * 16 + fr;
                float bb = b2[e * DD + col];
#pragma unroll
                for (int r = 0; r < 4; ++r) {
                    float v = acc[m][n][r] + bb;
                    Yb[(size_t)(row0 + r) * DD + col] = wp[r] * v;
                }
            }
        }
    }
}

// ---------------- combine: out[t] = Yb[pos0] + Yb[pos1]; bias passthrough ----------------
__global__ __launch_bounds__(256) void combine_kernel(
    const float* __restrict__ Yb, const int* __restrict__ pos_of,
    const float* __restrict__ bias, float* __restrict__ out, int T)
{
    int i = blockIdx.x * blockDim.x + threadIdx.x;
    int total = T * (DD / 4);
    if (i < total) {
        int t = i / (DD / 4);
        int c = (i % (DD / 4)) * 4;
        int p0 = pos_of[2 * t], p1 = pos_of[2 * t + 1];
        float4 v0 = *reinterpret_cast<const float4*>(&Yb[(size_t)p0 * DD + c]);
        float4 v1 = *reinterpret_cast<const float4*>(&Yb[(size_t)p1 * DD + c]);
        float4 o;
        o.x = v0.x + v1.x; o.y = v0.y + v1.y; o.z = v0.z + v1.z; o.w = v0.w + v1.w;
        *reinterpret_cast<float4*>(&out[(size_t)t * DD + c]) = o;
    } else if (i < total + DD / 4) {
        int c = (i - total) * 4;
        *reinterpret_cast<float4*>(&out[(size_t)T * DD + c]) =
            *reinterpret_cast<const float4*>(&bias[c]);
    }
}

extern "C" void kernel_launch(void* const* d_in, const int* in_sizes, int n_in,
                              void* d_out, int out_size, void* d_ws, size_t ws_size,
                              hipStream_t stream)
{
    const float* x    = (const float*)d_in[0];
    const float* gw   = (const float*)d_in[1];
    const float* gb   = (const float*)d_in[2];
    const float* w1   = (const float*)d_in[3];
    const float* b1   = (const float*)d_in[4];
    const float* w2   = (const float*)d_in[5];
    const float* b2   = (const float*)d_in[6];
    const float* bias = (const float*)d_in[7];
    float* out = (float*)d_out;

    int T = in_sizes[0] / DD;
    int nA = T * TOPK;
    int maxP = nA + NE * 128;

    char* ws = (char*)d_ws;
    size_t off = 0;
    auto alloc = [&](size_t bytes) -> char* {
        char* p = ws + off;
        off += (bytes + 255) & ~(size_t)255;
        return p;
    };
    unsigned short* w1b = (unsigned short*)alloc((size_t)NE * HH * DD * 2);
    unsigned short* w2b = (unsigned short*)alloc((size_t)NE * DD * HH * 2);
    unsigned short* Xe  = (unsigned short*)alloc((size_t)maxP * DD * 2);
    unsigned short* H1  = (unsigned short*)alloc((size_t)maxP * HH * 2);
    float*  Yb          = (float*)alloc((size_t)maxP * DD * 4);
    int*    topk_idx    = (int*)alloc((size_t)nA * 4);
    float*  topk_w      = (float*)alloc((size_t)nA * 4);
    int*    pos_of      = (int*)alloc((size_t)nA * 4);
    float*  wpos        = (float*)alloc((size_t)maxP * 4);
    int*    token_map   = (int*)alloc((size_t)maxP * 4);
    int*    ctrl        = (int*)alloc(64 * 4);

    size_t nW = (size_t)NE * HH * DD;

    hipLaunchKernelGGL(convert_kernel, dim3(4096), dim3(256), 0, stream,
                       w1, w2, w1b, w2b, nW);
    hipLaunchKernelGGL(init_kernel, dim3((maxP + 255) / 256), dim3(256), 0, stream,
                       token_map, ctrl, maxP);
    hipLaunchKernelGGL(gate_kernel, dim3((T + 3) / 4), dim3(256), 0, stream,
                       x, gw, gb, topk_idx, topk_w, ctrl, T);
    hipLaunchKernelGGL(offsets_kernel, dim3(1), dim3(64), 0, stream, ctrl);
    hipLaunchKernelGGL(scatter_kernel, dim3((nA + 255) / 256), dim3(256), 0, stream,
                       topk_idx, topk_w, ctrl, token_map, pos_of, wpos, nA);
    hipLaunchKernelGGL(gather_kernel, dim3((maxP * (DD / 4) + 255) / 256), dim3(256), 0, stream,
                       x, token_map, Xe, maxP);
    hipLaunchKernelGGL(gemm1_kernel, dim3(512), dim3(256), 0, stream,
                       Xe, w1b, b1, H1, ctrl);
    hipLaunchKernelGGL(gemm2_kernel, dim3(512), dim3(256), 0, stream,
                       H1, w2b, b2, wpos, Yb, ctrl);
    hipLaunchKernelGGL(combine_kernel, dim3((T * (DD / 4) + DD / 4 + 255) / 256, 1, 1), dim3(256), 0, stream,
                       Yb, pos_of, bias, out, T);
}